// Round 1
// baseline (590.039 us; speedup 1.0000x reference)
//
#include <hip/hip_runtime.h>
#include <hip/hip_bf16.h>
#include <math.h>

// Problem constants
#define B_    8
#define C_    64
#define H_    64
#define W_    64
#define NUM_EMBED 8192
#define DIMS  64
#define N_TOK (B_ * H_ * W_)           // 32768
#define N_ELEM (B_ * C_ * H_ * W_)     // 2097152

typedef short v8s __attribute__((ext_vector_type(8)));   // 8 bf16 = 4 VGPR
typedef float v4f __attribute__((ext_vector_type(4)));   // MFMA acc

#define MARGIN 0.011f   // rigorous bf16 bound 2*2^-8=0.0078, +40% headroom

// ---- helpers ---------------------------------------------------------------
__device__ __forceinline__ short bf16_rne(float x) {
    unsigned u = __float_as_uint(x);
    unsigned r = (u + 0x7FFFu + ((u >> 16) & 1u)) >> 16;
    return (short)r;
}
// monotone float->u32 (order-preserving, incl. negatives)
__device__ __forceinline__ unsigned mono(float f) {
    int b = __float_as_int(f);
    return (unsigned)(b ^ ((b >> 31) | 0x80000000));
}
__device__ __forceinline__ float demono(unsigned u) {
    int b = (u >> 31) ? (int)(u ^ 0x80000000u) : (int)~u;
    return __int_as_float(b);
}

// ---------------------------------------------------------------------------
// P1: inverse row norms of embedding. 4 rows/block, one wave per row.
// ---------------------------------------------------------------------------
__global__ void invnorm_kernel(const float* __restrict__ emb, float* __restrict__ invn) {
    int wave = threadIdx.x >> 6;
    int lane = threadIdx.x & 63;
    int row  = blockIdx.x * 4 + wave;
    float v = emb[row * DIMS + lane];
    float s = v * v;
    #pragma unroll
    for (int off = 1; off < 64; off <<= 1) s += __shfl_xor(s, off, 64);
    if (lane == 0) invn[row] = 1.0f / sqrtf(s);
}

// ---------------------------------------------------------------------------
// P2: build B fragments: en_frag[(ct*2+st)*64 + lane] = 8 bf16 of
//     en[code = ct*16 + (lane&15)][k = st*32 + (lane>>4)*8 + j]
// ---------------------------------------------------------------------------
__global__ void en_frag_kernel(const float* __restrict__ emb, const float* __restrict__ invn,
                               v8s* __restrict__ ef) {
    int ch = blockIdx.x * 256 + threadIdx.x;      // 0..65535
    int l  = ch & 63;
    int st = (ch >> 6) & 1;
    int ct = ch >> 7;
    int code = ct * 16 + (l & 15);
    int kb   = st * 32 + ((l >> 4) & 3) * 8;
    float rn = invn[code];
    v8s o;
    #pragma unroll
    for (int j = 0; j < 8; ++j) o[j] = bf16_rne(emb[code * DIMS + kb + j] * rn);
    ef[ch] = o;
}

// ---------------------------------------------------------------------------
// P3: z -> z_tok (fp32 token-major, for exact rescore)  +  A fragments
//     (normalized bf16). Block = one (b,h) row = 64 tokens = 4 M-tiles.
// ---------------------------------------------------------------------------
__global__ __launch_bounds__(256)
void z_prep_kernel(const float* __restrict__ z, float* __restrict__ z_tok,
                   v8s* __restrict__ af) {
    __shared__ float zs[64][65];   // [c][token_local], +1 pad
    __shared__ float part[4][64];
    __shared__ float rn[64];
    const int tid = threadIdx.x;
    const int w   = tid & 63;
    const int cg  = tid >> 6;
    const int bh  = blockIdx.x;            // 0..511
    const int b   = bh >> 6, h = bh & 63;

    const float* zb = z + (size_t)b * (C_ * H_ * W_) + h * W_;
    float ss = 0.f;
    #pragma unroll
    for (int cc = 0; cc < 16; ++cc) {
        int c = cg * 16 + cc;
        float v = zb[c * (H_ * W_) + w];
        zs[c][w] = v;
        ss += v * v;
    }
    part[cg][w] = ss;
    __syncthreads();
    if (tid < 64) {
        float s = part[0][tid] + part[1][tid] + part[2][tid] + part[3][tid];
        rn[tid] = 1.0f / sqrtf(s);
    }
    __syncthreads();

    // z_tok[t][c], coalesced in c
    {
        int c  = tid & 63;
        int tg = tid >> 6;
        #pragma unroll
        for (int i = 0; i < 16; ++i) {
            int tloc = tg * 16 + i;
            z_tok[(size_t)(bh * 64 + tloc) * DIMS + c] = zs[c][tloc];
        }
    }
    // A fragments: 512 chunks (4 mtiles x 2 ksteps x 64 lanes), 2 per thread
    #pragma unroll
    for (int ii = 0; ii < 2; ++ii) {
        int ch  = tid + ii * 256;
        int mtl = ch >> 7;
        int st  = (ch >> 6) & 1;
        int l   = ch & 63;
        int tloc = mtl * 16 + (l & 15);
        int kb   = st * 32 + ((l >> 4) & 3) * 8;
        float rr = rn[tloc];
        v8s o;
        #pragma unroll
        for (int j = 0; j < 8; ++j) o[j] = bf16_rne(zs[kb + j][tloc] * rr);
        af[(size_t)((bh * 4 + mtl) * 2 + st) * 64 + l] = o;
    }
}

// ---------------------------------------------------------------------------
// GEMM config:
//  - 512 threads (8 waves), RT=4 m-tiles/wave -> block M = 512 tokens
//  - codes split 8-way: block streams 1024 codes = 64 tiles of 16
//  - chunks of 16 tiles (256 codes) staged in 32 KB LDS, 4 chunks
//  - grid = 64 M-blocks x 8 splits = 512 blocks = 2 blocks/CU
// Pass1 is the ONLY full GEMM now. Per chunk it exports a per-token upper
// bound of the bf16 scores (mono>>16, rounded UP -> prune is a superset).
// ---------------------------------------------------------------------------
#define RT 4
#define CHUNK_TILES 16
#define TILES_PER_BLOCK 64
#define CHUNKS (TILES_PER_BLOCK / CHUNK_TILES)
#define NCHUNK_TOT 32                   // 8 splits * 4 chunks, 256 codes each

__global__ __launch_bounds__(512, 4)
void pass1_kernel(const v8s* __restrict__ af, const v8s* __restrict__ ef,
                  unsigned* __restrict__ tokmax,
                  unsigned short* __restrict__ cmax) {
    __shared__ v8s lds[CHUNK_TILES * 2 * 64];   // 32 KB
    const int tid  = threadIdx.x;
    const int lane = tid & 63;
    const int wave = tid >> 6;
    const int bm    = blockIdx.x >> 3;          // 0..63
    const int split = blockIdx.x & 7;
    const int tile0 = split * TILES_PER_BLOCK;

    const int mtb = bm * 32 + wave * RT;        // first m-tile of this wave
    v8s a[RT][2];
    #pragma unroll
    for (int r = 0; r < RT; ++r)
        #pragma unroll
        for (int s = 0; s < 2; ++s)
            a[r][s] = af[(size_t)((mtb + r) * 2 + s) * 64 + lane];

    v4f gm[RT];
    #pragma unroll
    for (int r = 0; r < RT; ++r) gm[r] = (v4f){-1e30f, -1e30f, -1e30f, -1e30f};

    const float4* gsrc = (const float4*)(ef + (size_t)tile0 * 2 * 64);
    float4* lf = (float4*)lds;
    float4 pre[4];
    #pragma unroll
    for (int i = 0; i < 4; ++i) pre[i] = gsrc[tid + i * 512];

    for (int c = 0; c < CHUNKS; ++c) {
        __syncthreads();
        #pragma unroll
        for (int i = 0; i < 4; ++i) lf[tid + i * 512] = pre[i];
        if (c + 1 < CHUNKS) {
            const float4* nx = gsrc + (size_t)(c + 1) * 2048;
            #pragma unroll
            for (int i = 0; i < 4; ++i) pre[i] = nx[tid + i * 512];
        }
        __syncthreads();

        v4f mxc[RT];
        #pragma unroll
        for (int r = 0; r < RT; ++r) mxc[r] = (v4f){-1e30f, -1e30f, -1e30f, -1e30f};

        #pragma unroll
        for (int j = 0; j < CHUNK_TILES; ++j) {
            v8s b0 = lds[(j * 2 + 0) * 64 + lane];
            v8s b1 = lds[(j * 2 + 1) * 64 + lane];
            #pragma unroll
            for (int r = 0; r < RT; ++r) {
                v4f t = (v4f){0.f, 0.f, 0.f, 0.f};
                t = __builtin_amdgcn_mfma_f32_16x16x32_bf16(a[r][0], b0, t, 0, 0, 0);
                t = __builtin_amdgcn_mfma_f32_16x16x32_bf16(a[r][1], b1, t, 0, 0, 0);
                mxc[r][0] = fmaxf(mxc[r][0], t[0]);
                mxc[r][1] = fmaxf(mxc[r][1], t[1]);
                mxc[r][2] = fmaxf(mxc[r][2], t[2]);
                mxc[r][3] = fmaxf(mxc[r][3], t[3]);
            }
        }

        // chunk-end: cross-lane reduce (16 code-columns) + export upper bound
        #pragma unroll
        for (int r = 0; r < RT; ++r)
            #pragma unroll
            for (int i = 0; i < 4; ++i) {
                float v = mxc[r][i];
                v = fmaxf(v, __shfl_xor(v, 1, 64));
                v = fmaxf(v, __shfl_xor(v, 2, 64));
                v = fmaxf(v, __shfl_xor(v, 4, 64));
                v = fmaxf(v, __shfl_xor(v, 8, 64));
                mxc[r][i] = v;
                gm[r][i]  = fmaxf(gm[r][i], v);
            }
        if ((lane & 15) == 0) {
            const int q   = lane >> 4;
            const int cid = split * CHUNKS + c;
            #pragma unroll
            for (int r = 0; r < RT; ++r)
                #pragma unroll
                for (int i = 0; i < 4; ++i) {
                    int tok = (mtb + r) * 16 + q * 4 + i;
                    // round UP so stored value >= true chunk max (safe prune)
                    cmax[tok * NCHUNK_TOT + cid] =
                        (unsigned short)((mono(mxc[r][i]) + 0xFFFFu) >> 16);
                }
        }
    }

    if ((lane & 15) == 0) {
        int q = lane >> 4;
        #pragma unroll
        for (int r = 0; r < RT; ++r)
            #pragma unroll
            for (int i = 0; i < 4; ++i) {
                int tok = (mtb + r) * 16 + q * 4 + i;
                atomicMax(&tokmax[tok], mono(gm[r][i]));
            }
    }
}

// ---------------------------------------------------------------------------
// Rescore: one wave per token. Read 32 chunk upper-bounds, qualify vs
// tokmax - MARGIN (expected ~1.3 chunks), exact fp32 rescore of qualifying
// chunks (4 codes/lane), argmax with tie -> smallest code. No atomics.
// ---------------------------------------------------------------------------
__global__ __launch_bounds__(256)
void rescore_kernel(const unsigned short* __restrict__ cmax,
                    const unsigned* __restrict__ tokmax,
                    const float* __restrict__ z_tok,
                    const float* __restrict__ emb,
                    const float* __restrict__ invn,
                    int* __restrict__ idx, float* __restrict__ idxmap) {
    __shared__ float zsh[4][64];
    const int tid   = threadIdx.x;
    const int lane  = tid & 63;
    const int wave  = tid >> 6;
    const int token = blockIdx.x * 4 + wave;

    zsh[wave][lane] = z_tok[(size_t)token * DIMS + lane];
    __syncthreads();

    float4 zr[16];
    {
        const float4* zp = (const float4*)zsh[wave];
        #pragma unroll
        for (int i = 0; i < 16; ++i) zr[i] = zp[i];
    }

    const float thrf = demono(tokmax[token]) - MARGIN;
    unsigned long long qual;
    {
        float ub = -1e30f;
        if (lane < NCHUNK_TOT)
            ub = demono(((unsigned)cmax[token * NCHUNK_TOT + lane]) << 16);
        qual = __ballot(ub >= thrf);
    }

    float bv = -1e30f;
    int   bc = 0x7FFFFFFF;
    while (qual) {
        const int cid = __ffsll(qual) - 1;
        qual &= qual - 1;
        const int base = cid * 256;
        #pragma unroll
        for (int k = 0; k < 4; ++k) {
            const int code = base + k * 64 + lane;
            const float4* ep = (const float4*)(emb + (size_t)code * DIMS);
            float s = 0.f;
            #pragma unroll
            for (int i = 0; i < 16; ++i) {
                float4 e = ep[i];
                s = fmaf(zr[i].x, e.x, s);
                s = fmaf(zr[i].y, e.y, s);
                s = fmaf(zr[i].z, e.z, s);
                s = fmaf(zr[i].w, e.w, s);
            }
            const float val = s * invn[code];
            if (val > bv || (val == bv && code < bc)) { bv = val; bc = code; }
        }
    }
    #pragma unroll
    for (int off = 1; off < 64; off <<= 1) {
        float ov = __shfl_xor(bv, off, 64);
        int   oc = __shfl_xor(bc, off, 64);
        if (ov > bv || (ov == bv && oc < bc)) { bv = ov; bc = oc; }
    }
    if (lane == 0) {
        idx[token]    = bc;
        idxmap[token] = (float)bc;
    }
}

// ---------------------------------------------------------------------------
// K3: gather z_q, out = zv + (q - zv), SSE partial, histogram.
// ---------------------------------------------------------------------------
__global__ void gather_loss_kernel(const float* __restrict__ z,
                                   const float* __restrict__ emb,
                                   const int* __restrict__ idx,
                                   float* __restrict__ out,
                                   float* __restrict__ partial,
                                   int* __restrict__ hist) {
    __shared__ float red[256];
    const int tid  = threadIdx.x;
    const int lane = tid & 63;   // w
    const int wave = tid >> 6;
    const int bt   = blockIdx.x; // 0..511
    const int b    = bt >> 6;
    const int h    = bt & 63;

    const int t  = bt * 64 + lane;
    const int id = idx[t];
    const long base = (long)b * (C_ * H_ * W_) + h * W_ + lane;

    float sse = 0.f;
    #pragma unroll
    for (int cc = 0; cc < 16; ++cc) {
        const int c = wave * 16 + cc;
        const float q  = emb[id * DIMS + c];
        const float zv = z[base + (long)c * (H_ * W_)];
        out[base + (long)c * (H_ * W_)] = zv + (q - zv);  // exact ref expression
        const float d = q - zv;
        sse += d * d;
    }

    red[tid] = sse;
    __syncthreads();
    for (int s = 128; s > 0; s >>= 1) {
        if (tid < s) red[tid] += red[tid + s];
        __syncthreads();
    }
    if (tid == 0) partial[bt] = red[0];
    if (wave == 0) atomicAdd(&hist[id], 1);
}

// ---------------------------------------------------------------------------
// K4: finalize loss + perplexity. One block of 256 threads.
// ---------------------------------------------------------------------------
__global__ void finalize_kernel(const float* __restrict__ partial,
                                const int* __restrict__ hist,
                                float* __restrict__ out_scal) {
    __shared__ double red[256];
    const int tid = threadIdx.x;

    double s = 0.0;
    for (int i = tid; i < 512; i += 256) s += (double)partial[i];
    red[tid] = s;
    __syncthreads();
    for (int st = 128; st > 0; st >>= 1) {
        if (tid < st) red[tid] += red[tid + st];
        __syncthreads();
    }
    const double sse = red[0];
    __syncthreads();

    double e = 0.0;
    for (int k = tid; k < NUM_EMBED; k += 256) {
        float p = (float)hist[k] / (float)N_TOK;
        e += (double)(p * logf(p + 1e-10f));
    }
    red[tid] = e;
    __syncthreads();
    for (int st = 128; st > 0; st >>= 1) {
        if (tid < st) red[tid] += red[tid + st];
        __syncthreads();
    }
    if (tid == 0) {
        out_scal[0] = (float)(1.25 * sse / (double)N_ELEM);
        out_scal[1] = expf(-(float)red[0]);
    }
}

// ---------------------------------------------------------------------------
extern "C" void kernel_launch(void* const* d_in, const int* in_sizes, int n_in,
                              void* d_out, int out_size, void* d_ws, size_t ws_size,
                              hipStream_t stream) {
    const float* z   = (const float*)d_in[0];
    const float* emb = (const float*)d_in[1];
    float* o = (float*)d_out;

    // workspace layout (7.33 MB total)
    char* ws = (char*)d_ws;
    v8s*  af      = (v8s*)ws;                                      // 4 MB
    v8s*  ef      = (v8s*)(ws + 4194304);                          // 1 MB
    unsigned short* cmaxb = (unsigned short*)(ws + 5242880);       // 2 MB (32768*32 u16)
    unsigned* tokmax = (unsigned*)(ws + 7340032);                  // 128 KB
    int*   idx     = (int*)(ws + 7471104);                         // 128 KB
    float* invn    = (float*)(ws + 7602176);                       // 32 KB
    int*   hist    = (int*)(ws + 7634944);                         // 32 KB
    float* partial = (float*)(ws + 7667712);                       // 2 KB

    float* out_q      = o;                  // 2097152 floats
    float* out_scal   = o + N_ELEM;         // loss, perplexity
    float* out_idxmap = o + N_ELEM + 2;     // 32768 floats
    float* z_tok      = o;                  // reuse out_q region as fp32 token-major
                                            // scratch; overwritten by gather later

    hipMemsetAsync(tokmax, 0, N_TOK * sizeof(unsigned), stream);
    hipMemsetAsync(hist,   0, NUM_EMBED * sizeof(int), stream);

    invnorm_kernel<<<NUM_EMBED / 4, 256, 0, stream>>>(emb, invn);
    en_frag_kernel<<<256, 256, 0, stream>>>(emb, invn, ef);
    z_prep_kernel<<<512, 256, 0, stream>>>(z, z_tok, af);
    pass1_kernel<<<512, 512, 0, stream>>>(af, ef, tokmax, cmaxb);
    rescore_kernel<<<N_TOK / 4, 256, 0, stream>>>(cmaxb, tokmax, z_tok, emb, invn,
                                                  idx, out_idxmap);
    gather_loss_kernel<<<N_TOK / 64, 256, 0, stream>>>(z, emb, idx, out_q, partial, hist);
    finalize_kernel<<<1, 256, 0, stream>>>(partial, hist, out_scal);
}

// Round 3
// 395.867 us; speedup vs baseline: 1.4905x; 1.4905x over previous
//
#include <hip/hip_runtime.h>
#include <hip/hip_bf16.h>
#include <math.h>

// Problem constants
#define B_    8
#define C_    64
#define H_    64
#define W_    64
#define NUM_EMBED 8192
#define DIMS  64
#define N_TOK (B_ * H_ * W_)           // 32768
#define N_ELEM (B_ * C_ * H_ * W_)     // 2097152

typedef short v8s __attribute__((ext_vector_type(8)));   // 8 bf16 = 4 VGPR
typedef float v4f __attribute__((ext_vector_type(4)));   // MFMA acc

#define MARGIN 0.011f   // rigorous bf16 bound 2*2^-8=0.0078, +40% headroom

// ---- helpers ---------------------------------------------------------------
__device__ __forceinline__ short bf16_rne(float x) {
    unsigned u = __float_as_uint(x);
    unsigned r = (u + 0x7FFFu + ((u >> 16) & 1u)) >> 16;
    return (short)r;
}
// monotone float->u32 (order-preserving, incl. negatives)
__device__ __forceinline__ unsigned mono(float f) {
    int b = __float_as_int(f);
    return (unsigned)(b ^ ((b >> 31) | 0x80000000));
}
__device__ __forceinline__ float demono(unsigned u) {
    int b = (u >> 31) ? (int)(u ^ 0x80000000u) : (int)~u;
    return __int_as_float(b);
}

// ---------------------------------------------------------------------------
// P1: inverse row norms of embedding. 4 rows/block, one wave per row.
// ---------------------------------------------------------------------------
__global__ void invnorm_kernel(const float* __restrict__ emb, float* __restrict__ invn) {
    int wave = threadIdx.x >> 6;
    int lane = threadIdx.x & 63;
    int row  = blockIdx.x * 4 + wave;
    float v = emb[row * DIMS + lane];
    float s = v * v;
    #pragma unroll
    for (int off = 1; off < 64; off <<= 1) s += __shfl_xor(s, off, 64);
    if (lane == 0) invn[row] = 1.0f / sqrtf(s);
}

// ---------------------------------------------------------------------------
// P2: build B fragments: en_frag[(ct*2+st)*64 + lane] = 8 bf16 of
//     en[code = ct*16 + (lane&15)][k = st*32 + (lane>>4)*8 + j]
// ---------------------------------------------------------------------------
__global__ void en_frag_kernel(const float* __restrict__ emb, const float* __restrict__ invn,
                               v8s* __restrict__ ef) {
    int ch = blockIdx.x * 256 + threadIdx.x;      // 0..65535
    int l  = ch & 63;
    int st = (ch >> 6) & 1;
    int ct = ch >> 7;
    int code = ct * 16 + (l & 15);
    int kb   = st * 32 + ((l >> 4) & 3) * 8;
    float rn = invn[code];
    v8s o;
    #pragma unroll
    for (int j = 0; j < 8; ++j) o[j] = bf16_rne(emb[code * DIMS + kb + j] * rn);
    ef[ch] = o;
}

// ---------------------------------------------------------------------------
// P3: z -> A fragments (normalized bf16). Block = one (b,h) row = 64 tokens.
// (z_tok eliminated: rescore reads z directly now.)
// ---------------------------------------------------------------------------
__global__ __launch_bounds__(256)
void z_prep_kernel(const float* __restrict__ z, v8s* __restrict__ af) {
    __shared__ float zs[64][65];   // [c][token_local], +1 pad
    __shared__ float part[4][64];
    __shared__ float rn[64];
    const int tid = threadIdx.x;
    const int w   = tid & 63;
    const int cg  = tid >> 6;
    const int bh  = blockIdx.x;            // 0..511
    const int b   = bh >> 6, h = bh & 63;

    const float* zb = z + (size_t)b * (C_ * H_ * W_) + h * W_;
    float ss = 0.f;
    #pragma unroll
    for (int cc = 0; cc < 16; ++cc) {
        int c = cg * 16 + cc;
        float v = zb[c * (H_ * W_) + w];
        zs[c][w] = v;
        ss += v * v;
    }
    part[cg][w] = ss;
    __syncthreads();
    if (tid < 64) {
        float s = part[0][tid] + part[1][tid] + part[2][tid] + part[3][tid];
        rn[tid] = 1.0f / sqrtf(s);
    }
    __syncthreads();

    // A fragments: 512 chunks (4 mtiles x 2 ksteps x 64 lanes), 2 per thread
    #pragma unroll
    for (int ii = 0; ii < 2; ++ii) {
        int ch  = tid + ii * 256;
        int mtl = ch >> 7;
        int st  = (ch >> 6) & 1;
        int l   = ch & 63;
        int tloc = mtl * 16 + (l & 15);
        int kb   = st * 32 + ((l >> 4) & 3) * 8;
        float rr = rn[tloc];
        v8s o;
        #pragma unroll
        for (int j = 0; j < 8; ++j) o[j] = bf16_rne(zs[kb + j][tloc] * rr);
        af[(size_t)((bh * 4 + mtl) * 2 + st) * 64 + l] = o;
    }
}

// ---------------------------------------------------------------------------
// GEMM config (pass1 = the only GEMM):
//  - 512 threads (8 waves), RT=4 m-tiles/wave -> block M = 512 tokens
//  - codes split 8-way: block streams 1024 codes = 64 tiles of 16
//  - chunks of 16 tiles (256 codes) staged in 32 KB LDS, 4 chunks
//  - per SUB-chunk of 4 tiles (64 codes), export per-token upper bound
//    (mono>>16, rounded UP -> prune is a strict superset)
//  - grid = 64 M-blocks x 8 splits = 512 blocks = 2 blocks/CU
// ---------------------------------------------------------------------------
#define RT 4
#define CHUNK_TILES 16
#define TILES_PER_BLOCK 64
#define CHUNKS (TILES_PER_BLOCK / CHUNK_TILES)
#define SUBT 4                          // tiles per bound group (64 codes)
#define NSUB (CHUNK_TILES / SUBT)       // 4 sub-chunks per LDS chunk
#define NCHUNK_TOT 128                  // 8 splits * 4 chunks * 4 sub = 128

__global__ __launch_bounds__(512, 4)
void pass1_kernel(const v8s* __restrict__ af, const v8s* __restrict__ ef,
                  unsigned* __restrict__ tokmax,
                  unsigned short* __restrict__ cmax) {
    __shared__ v8s lds[CHUNK_TILES * 2 * 64];   // 32 KB
    const int tid  = threadIdx.x;
    const int lane = tid & 63;
    const int wave = tid >> 6;
    const int bm    = blockIdx.x >> 3;          // 0..63
    const int split = blockIdx.x & 7;
    const int tile0 = split * TILES_PER_BLOCK;

    const int mtb = bm * 32 + wave * RT;        // first m-tile of this wave
    v8s a[RT][2];
    #pragma unroll
    for (int r = 0; r < RT; ++r)
        #pragma unroll
        for (int s = 0; s < 2; ++s)
            a[r][s] = af[(size_t)((mtb + r) * 2 + s) * 64 + lane];

    v4f gm[RT];
    #pragma unroll
    for (int r = 0; r < RT; ++r) gm[r] = (v4f){-1e30f, -1e30f, -1e30f, -1e30f};

    const float4* gsrc = (const float4*)(ef + (size_t)tile0 * 2 * 64);
    float4* lf = (float4*)lds;
    float4 pre[4];
    #pragma unroll
    for (int i = 0; i < 4; ++i) pre[i] = gsrc[tid + i * 512];

    for (int c = 0; c < CHUNKS; ++c) {
        __syncthreads();
        #pragma unroll
        for (int i = 0; i < 4; ++i) lf[tid + i * 512] = pre[i];
        if (c + 1 < CHUNKS) {
            const float4* nx = gsrc + (size_t)(c + 1) * 2048;
            #pragma unroll
            for (int i = 0; i < 4; ++i) pre[i] = nx[tid + i * 512];
        }
        __syncthreads();

        #pragma unroll
        for (int jj = 0; jj < NSUB; ++jj) {
            v4f mxc[RT];
            #pragma unroll
            for (int r = 0; r < RT; ++r)
                mxc[r] = (v4f){-1e30f, -1e30f, -1e30f, -1e30f};

            #pragma unroll
            for (int j4 = 0; j4 < SUBT; ++j4) {
                const int j = jj * SUBT + j4;
                v8s b0 = lds[(j * 2 + 0) * 64 + lane];
                v8s b1 = lds[(j * 2 + 1) * 64 + lane];
                #pragma unroll
                for (int r = 0; r < RT; ++r) {
                    v4f t = (v4f){0.f, 0.f, 0.f, 0.f};
                    t = __builtin_amdgcn_mfma_f32_16x16x32_bf16(a[r][0], b0, t, 0, 0, 0);
                    t = __builtin_amdgcn_mfma_f32_16x16x32_bf16(a[r][1], b1, t, 0, 0, 0);
                    mxc[r][0] = fmaxf(mxc[r][0], t[0]);
                    mxc[r][1] = fmaxf(mxc[r][1], t[1]);
                    mxc[r][2] = fmaxf(mxc[r][2], t[2]);
                    mxc[r][3] = fmaxf(mxc[r][3], t[3]);
                }
            }

            // sub-chunk end: reduce over 16 code columns, export upper bound
            #pragma unroll
            for (int r = 0; r < RT; ++r)
                #pragma unroll
                for (int i = 0; i < 4; ++i) {
                    float v = mxc[r][i];
                    v = fmaxf(v, __shfl_xor(v, 1, 64));
                    v = fmaxf(v, __shfl_xor(v, 2, 64));
                    v = fmaxf(v, __shfl_xor(v, 4, 64));
                    v = fmaxf(v, __shfl_xor(v, 8, 64));
                    mxc[r][i] = v;
                    gm[r][i]  = fmaxf(gm[r][i], v);
                }
            if ((lane & 15) == 0) {
                const int q   = lane >> 4;
                const int cid = split * (CHUNKS * NSUB) + c * NSUB + jj;
                #pragma unroll
                for (int r = 0; r < RT; ++r)
                    #pragma unroll
                    for (int i = 0; i < 4; ++i) {
                        int tok = (mtb + r) * 16 + q * 4 + i;
                        // round UP: stored >= true sub-chunk max (safe prune)
                        cmax[(size_t)tok * NCHUNK_TOT + cid] =
                            (unsigned short)((mono(mxc[r][i]) + 0xFFFFu) >> 16);
                    }
            }
        }
    }

    if ((lane & 15) == 0) {
        int q = lane >> 4;
        #pragma unroll
        for (int r = 0; r < RT; ++r)
            #pragma unroll
            for (int i = 0; i < 4; ++i) {
                int tok = (mtb + r) * 16 + q * 4 + i;
                atomicMax(&tokmax[tok], mono(gm[r][i]));
            }
    }
}

// ---------------------------------------------------------------------------
// Rescore: one wave per token, 4 tokens per block.
// Read 128 sub-chunk upper-bounds, qualify vs tokmax - MARGIN (~1.5 of 128),
// exact fp32 rescore of qualifying 64-code sub-chunks with COALESCED loads:
// one float4 load instruction covers 4 complete code rows (lane l reads row
// i*4 + (l>>4), bytes (l&15)*16), 16-lane xor-tree completes each dot.
// ---------------------------------------------------------------------------
__global__ __launch_bounds__(256)
void rescore_kernel(const unsigned short* __restrict__ cmax,
                    const unsigned* __restrict__ tokmax,
                    const float* __restrict__ z,
                    const float* __restrict__ emb,
                    const float* __restrict__ invn,
                    int* __restrict__ idx, float* __restrict__ idxmap) {
    __shared__ float zsh[4][64];
    const int tid   = threadIdx.x;
    const int lane  = tid & 63;
    const int wv    = tid >> 6;
    const int token = blockIdx.x * 4 + wv;

    // cooperative z load: lane = channel, token's (b, h*64+w)
    {
        const int b = token >> 12, hw = token & 4095;
        zsh[wv][lane] = z[(size_t)b * (C_ * H_ * W_) + (size_t)lane * (H_ * W_) + hw];
    }
    __syncthreads();

    const float4 zr = ((const float4*)zsh[wv])[lane & 15];
    const float thrf = demono(tokmax[token]) - MARGIN;

    const unsigned short* cm = cmax + (size_t)token * NCHUNK_TOT;
    float ub0 = demono(((unsigned)cm[lane]) << 16);
    float ub1 = demono(((unsigned)cm[64 + lane]) << 16);
    unsigned long long q0 = __ballot(ub0 >= thrf);
    unsigned long long q1 = __ballot(ub1 >= thrf);

    float bv = -1e30f;
    int   bc = 0x7FFFFFFF;
    const int g  = lane >> 4;      // row-group 0..3
    const int li = lane & 15;

    #pragma unroll
    for (int half = 0; half < 2; ++half) {
        unsigned long long q = half ? q1 : q0;
        const int cb = half ? 64 : 0;
        while (q) {
            const int cid = cb + (__ffsll(q) - 1);
            q &= q - 1;
            const int rbase = cid * 64;       // first code of sub-chunk
            #pragma unroll
            for (int i = 0; i < 16; ++i) {
                const int code = rbase + i * 4 + g;
                const float4 e = ((const float4*)(emb + (size_t)code * DIMS))[li];
                float s = zr.x * e.x;
                s = fmaf(zr.y, e.y, s);
                s = fmaf(zr.z, e.z, s);
                s = fmaf(zr.w, e.w, s);
                s += __shfl_xor(s, 1, 64);
                s += __shfl_xor(s, 2, 64);
                s += __shfl_xor(s, 4, 64);
                s += __shfl_xor(s, 8, 64);
                const float val = s * invn[code];
                if (val > bv || (val == bv && code < bc)) { bv = val; bc = code; }
            }
        }
    }
    // merge the 4 row-groups (16-lane groups already agree)
    #pragma unroll
    for (int off = 1; off < 64; off <<= 1) {
        float ov = __shfl_xor(bv, off, 64);
        int   oc = __shfl_xor(bc, off, 64);
        if (ov > bv || (ov == bv && oc < bc)) { bv = ov; bc = oc; }
    }
    if (lane == 0) {
        idx[token]    = bc;
        idxmap[token] = (float)bc;
    }
}

// ---------------------------------------------------------------------------
// K3: gather z_q, out = zv + (q - zv), SSE partial, histogram.
// ---------------------------------------------------------------------------
__global__ void gather_loss_kernel(const float* __restrict__ z,
                                   const float* __restrict__ emb,
                                   const int* __restrict__ idx,
                                   float* __restrict__ out,
                                   float* __restrict__ partial,
                                   int* __restrict__ hist) {
    __shared__ float red[256];
    const int tid  = threadIdx.x;
    const int lane = tid & 63;   // w
    const int wave = tid >> 6;
    const int bt   = blockIdx.x; // 0..511
    const int b    = bt >> 6;
    const int h    = bt & 63;

    const int t  = bt * 64 + lane;
    const int id = idx[t];
    const long base = (long)b * (C_ * H_ * W_) + h * W_ + lane;

    float sse = 0.f;
    #pragma unroll
    for (int cc = 0; cc < 16; ++cc) {
        const int c = wave * 16 + cc;
        const float q  = emb[id * DIMS + c];
        const float zv = z[base + (long)c * (H_ * W_)];
        out[base + (long)c * (H_ * W_)] = zv + (q - zv);  // exact ref expression
        const float d = q - zv;
        sse += d * d;
    }

    red[tid] = sse;
    __syncthreads();
    for (int s = 128; s > 0; s >>= 1) {
        if (tid < s) red[tid] += red[tid + s];
        __syncthreads();
    }
    if (tid == 0) partial[bt] = red[0];
    if (wave == 0) atomicAdd(&hist[id], 1);
}

// ---------------------------------------------------------------------------
// K4: finalize loss + perplexity. One block of 256 threads.
// ---------------------------------------------------------------------------
__global__ void finalize_kernel(const float* __restrict__ partial,
                                const int* __restrict__ hist,
                                float* __restrict__ out_scal) {
    __shared__ double red[256];
    const int tid = threadIdx.x;

    double s = 0.0;
    for (int i = tid; i < 512; i += 256) s += (double)partial[i];
    red[tid] = s;
    __syncthreads();
    for (int st = 128; st > 0; st >>= 1) {
        if (tid < st) red[tid] += red[tid + st];
        __syncthreads();
    }
    const double sse = red[0];
    __syncthreads();

    double e = 0.0;
    for (int k = tid; k < NUM_EMBED; k += 256) {
        float p = (float)hist[k] / (float)N_TOK;
        e += (double)(p * logf(p + 1e-10f));
    }
    red[tid] = e;
    __syncthreads();
    for (int st = 128; st > 0; st >>= 1) {
        if (tid < st) red[tid] += red[tid + st];
        __syncthreads();
    }
    if (tid == 0) {
        out_scal[0] = (float)(1.25 * sse / (double)N_ELEM);
        out_scal[1] = expf(-(float)red[0]);
    }
}

// ---------------------------------------------------------------------------
extern "C" void kernel_launch(void* const* d_in, const int* in_sizes, int n_in,
                              void* d_out, int out_size, void* d_ws, size_t ws_size,
                              hipStream_t stream) {
    const float* z   = (const float*)d_in[0];
    const float* emb = (const float*)d_in[1];
    float* o = (float*)d_out;

    // workspace layout (5.57 MB base; proven available)
    char* ws = (char*)d_ws;
    v8s*  af      = (v8s*)ws;                                      // 4 MB
    v8s*  ef      = (v8s*)(ws + 4194304);                          // 1 MB
    unsigned* tokmax = (unsigned*)(ws + 5242880);                  // 128 KB
    int*   idx     = (int*)(ws + 5373952);                         // 128 KB
    float* invn    = (float*)(ws + 5505024);                       // 32 KB
    int*   hist    = (int*)(ws + 5537792);                         // 32 KB
    float* partial = (float*)(ws + 5570560);                       // 2 KB

    float* out_q      = o;                  // 2097152 floats
    float* out_scal   = o + N_ELEM;         // loss, perplexity
    float* out_idxmap = o + N_ELEM + 2;     // 32768 floats

    // cmax: u16[32768][128] = 8 MB. Prefer workspace if it is large enough;
    // otherwise use the out_q region (8.39 MB needed, 8.51 MB available;
    // written by pass1, read by rescore, overwritten by gather_loss after).
    unsigned short* cmaxb;
    if (ws_size >= (size_t)5572608 + 8388608)
        cmaxb = (unsigned short*)(ws + 5572608);
    else
        cmaxb = (unsigned short*)o;

    hipMemsetAsync(tokmax, 0, N_TOK * sizeof(unsigned), stream);
    hipMemsetAsync(hist,   0, NUM_EMBED * sizeof(int), stream);

    invnorm_kernel<<<NUM_EMBED / 4, 256, 0, stream>>>(emb, invn);
    en_frag_kernel<<<256, 256, 0, stream>>>(emb, invn, ef);
    z_prep_kernel<<<512, 256, 0, stream>>>(z, af);
    pass1_kernel<<<512, 512, 0, stream>>>(af, ef, tokmax, cmaxb);
    rescore_kernel<<<N_TOK / 4, 256, 0, stream>>>(cmaxb, tokmax, z, emb, invn,
                                                  idx, out_idxmap);
    gather_loss_kernel<<<N_TOK / 64, 256, 0, stream>>>(z, emb, idx, out_q, partial, hist);
    finalize_kernel<<<1, 256, 0, stream>>>(partial, hist, out_scal);
}

// Round 4
// 296.060 us; speedup vs baseline: 1.9930x; 1.3371x over previous
//
#include <hip/hip_runtime.h>
#include <hip/hip_bf16.h>
#include <math.h>

// Problem constants
#define B_    8
#define C_    64
#define H_    64
#define W_    64
#define NUM_EMBED 8192
#define DIMS  64
#define N_TOK (B_ * H_ * W_)           // 32768
#define N_ELEM (B_ * C_ * H_ * W_)     // 2097152

typedef short v8s __attribute__((ext_vector_type(8)));   // 8 bf16 = 4 VGPR
typedef float v4f __attribute__((ext_vector_type(4)));   // MFMA acc

#define MARGIN 0.011f   // rigorous bf16 bound 2*2^-8=0.0078, +40% headroom

// ---- helpers ---------------------------------------------------------------
__device__ __forceinline__ short bf16_rne(float x) {
    unsigned u = __float_as_uint(x);
    unsigned r = (u + 0x7FFFu + ((u >> 16) & 1u)) >> 16;
    return (short)r;
}
// monotone float->u32 (order-preserving, incl. negatives)
__device__ __forceinline__ unsigned mono(float f) {
    int b = __float_as_int(f);
    return (unsigned)(b ^ ((b >> 31) | 0x80000000));
}
__device__ __forceinline__ float demono(unsigned u) {
    int b = (u >> 31) ? (int)(u ^ 0x80000000u) : (int)~u;
    return __int_as_float(b);
}
__device__ __forceinline__ unsigned short ub16(float x) {
    // 16-bit monotone upper bound (round UP)
    return (unsigned short)((mono(x) + 0xFFFFu) >> 16);
}

// ---------------------------------------------------------------------------
// P1: inverse row norms of embedding. 4 rows/block, one wave per row.
// ---------------------------------------------------------------------------
__global__ void invnorm_kernel(const float* __restrict__ emb, float* __restrict__ invn) {
    int wave = threadIdx.x >> 6;
    int lane = threadIdx.x & 63;
    int row  = blockIdx.x * 4 + wave;
    float v = emb[row * DIMS + lane];
    float s = v * v;
    #pragma unroll
    for (int off = 1; off < 64; off <<= 1) s += __shfl_xor(s, off, 64);
    if (lane == 0) invn[row] = 1.0f / sqrtf(s);
}

// ---------------------------------------------------------------------------
// P2: build B fragments: en_frag[(ct*2+st)*64 + lane] = 8 bf16 of
//     en[code = ct*16 + (lane&15)][k = st*32 + (lane>>4)*8 + j]
// ---------------------------------------------------------------------------
__global__ void en_frag_kernel(const float* __restrict__ emb, const float* __restrict__ invn,
                               v8s* __restrict__ ef) {
    int ch = blockIdx.x * 256 + threadIdx.x;      // 0..65535
    int l  = ch & 63;
    int st = (ch >> 6) & 1;
    int ct = ch >> 7;
    int code = ct * 16 + (l & 15);
    int kb   = st * 32 + ((l >> 4) & 3) * 8;
    float rn = invn[code];
    v8s o;
    #pragma unroll
    for (int j = 0; j < 8; ++j) o[j] = bf16_rne(emb[code * DIMS + kb + j] * rn);
    ef[ch] = o;
}

// ---------------------------------------------------------------------------
// P3: z -> A fragments (normalized bf16). Block = one (b,h) row = 64 tokens.
// ---------------------------------------------------------------------------
__global__ __launch_bounds__(256)
void z_prep_kernel(const float* __restrict__ z, v8s* __restrict__ af) {
    __shared__ float zs[64][65];   // [c][token_local], +1 pad
    __shared__ float part[4][64];
    __shared__ float rn[64];
    const int tid = threadIdx.x;
    const int w   = tid & 63;
    const int cg  = tid >> 6;
    const int bh  = blockIdx.x;            // 0..511
    const int b   = bh >> 6, h = bh & 63;

    const float* zb = z + (size_t)b * (C_ * H_ * W_) + h * W_;
    float ss = 0.f;
    #pragma unroll
    for (int cc = 0; cc < 16; ++cc) {
        int c = cg * 16 + cc;
        float v = zb[c * (H_ * W_) + w];
        zs[c][w] = v;
        ss += v * v;
    }
    part[cg][w] = ss;
    __syncthreads();
    if (tid < 64) {
        float s = part[0][tid] + part[1][tid] + part[2][tid] + part[3][tid];
        rn[tid] = 1.0f / sqrtf(s);
    }
    __syncthreads();

    // A fragments: 512 chunks (4 mtiles x 2 ksteps x 64 lanes), 2 per thread
    #pragma unroll
    for (int ii = 0; ii < 2; ++ii) {
        int ch  = tid + ii * 256;
        int mtl = ch >> 7;
        int st  = (ch >> 6) & 1;
        int l   = ch & 63;
        int tloc = mtl * 16 + (l & 15);
        int kb   = st * 32 + ((l >> 4) & 3) * 8;
        float rr = rn[tloc];
        v8s o;
        #pragma unroll
        for (int j = 0; j < 8; ++j) o[j] = bf16_rne(zs[kb + j][tloc] * rr);
        af[(size_t)((bh * 4 + mtl) * 2 + st) * 64 + l] = o;
    }
}

// ---------------------------------------------------------------------------
// GEMM config (pass1 = the only GEMM):
//  - 512 threads (8 waves), RT=4 m-tiles/wave -> block M = 512 tokens
//  - codes split 8-way: block streams 1024 codes = 64 tiles of 16
//  - chunks of 16 tiles (256 codes) staged in 32 KB LDS, 4 chunks
//  - per SUB-chunk of 4 tiles (64 codes), export per-token upper bound
//  - cmax layout is CID-MAJOR: cmax[cid][token]. At each export event the
//    wave's 64 consecutive tokens form a contiguous 128 B span; each active
//    lane stores one ushort4 (4 consecutive tokens) -> fully coalesced,
//    zero partial-line RMW (round-3 lesson: tok-major cost 885 MB of HBM).
// ---------------------------------------------------------------------------
#define RT 4
#define CHUNK_TILES 16
#define TILES_PER_BLOCK 64
#define CHUNKS (TILES_PER_BLOCK / CHUNK_TILES)
#define SUBT 4                          // tiles per bound group (64 codes)
#define NSUB (CHUNK_TILES / SUBT)       // 4 sub-chunks per LDS chunk
#define NCHUNK_TOT 128                  // 8 splits * 4 chunks * 4 sub = 128

__global__ __launch_bounds__(512, 4)
void pass1_kernel(const v8s* __restrict__ af, const v8s* __restrict__ ef,
                  unsigned* __restrict__ tokmax,
                  unsigned short* __restrict__ cmax) {
    __shared__ v8s lds[CHUNK_TILES * 2 * 64];   // 32 KB
    const int tid  = threadIdx.x;
    const int lane = tid & 63;
    const int wave = tid >> 6;
    const int bm    = blockIdx.x >> 3;          // 0..63
    const int split = blockIdx.x & 7;
    const int tile0 = split * TILES_PER_BLOCK;

    const int mtb = bm * 32 + wave * RT;        // first m-tile of this wave
    v8s a[RT][2];
    #pragma unroll
    for (int r = 0; r < RT; ++r)
        #pragma unroll
        for (int s = 0; s < 2; ++s)
            a[r][s] = af[(size_t)((mtb + r) * 2 + s) * 64 + lane];

    v4f gm[RT];
    #pragma unroll
    for (int r = 0; r < RT; ++r) gm[r] = (v4f){-1e30f, -1e30f, -1e30f, -1e30f};

    const float4* gsrc = (const float4*)(ef + (size_t)tile0 * 2 * 64);
    float4* lf = (float4*)lds;
    float4 pre[4];
    #pragma unroll
    for (int i = 0; i < 4; ++i) pre[i] = gsrc[tid + i * 512];

    for (int c = 0; c < CHUNKS; ++c) {
        __syncthreads();
        #pragma unroll
        for (int i = 0; i < 4; ++i) lf[tid + i * 512] = pre[i];
        if (c + 1 < CHUNKS) {
            const float4* nx = gsrc + (size_t)(c + 1) * 2048;
            #pragma unroll
            for (int i = 0; i < 4; ++i) pre[i] = nx[tid + i * 512];
        }
        __syncthreads();

        #pragma unroll
        for (int jj = 0; jj < NSUB; ++jj) {
            v4f mxc[RT];
            #pragma unroll
            for (int r = 0; r < RT; ++r)
                mxc[r] = (v4f){-1e30f, -1e30f, -1e30f, -1e30f};

            #pragma unroll
            for (int j4 = 0; j4 < SUBT; ++j4) {
                const int j = jj * SUBT + j4;
                v8s b0 = lds[(j * 2 + 0) * 64 + lane];
                v8s b1 = lds[(j * 2 + 1) * 64 + lane];
                #pragma unroll
                for (int r = 0; r < RT; ++r) {
                    v4f t = (v4f){0.f, 0.f, 0.f, 0.f};
                    t = __builtin_amdgcn_mfma_f32_16x16x32_bf16(a[r][0], b0, t, 0, 0, 0);
                    t = __builtin_amdgcn_mfma_f32_16x16x32_bf16(a[r][1], b1, t, 0, 0, 0);
                    mxc[r][0] = fmaxf(mxc[r][0], t[0]);
                    mxc[r][1] = fmaxf(mxc[r][1], t[1]);
                    mxc[r][2] = fmaxf(mxc[r][2], t[2]);
                    mxc[r][3] = fmaxf(mxc[r][3], t[3]);
                }
            }

            // sub-chunk end: reduce over 16 code columns, export upper bound
            #pragma unroll
            for (int r = 0; r < RT; ++r)
                #pragma unroll
                for (int i = 0; i < 4; ++i) {
                    float v = mxc[r][i];
                    v = fmaxf(v, __shfl_xor(v, 1, 64));
                    v = fmaxf(v, __shfl_xor(v, 2, 64));
                    v = fmaxf(v, __shfl_xor(v, 4, 64));
                    v = fmaxf(v, __shfl_xor(v, 8, 64));
                    mxc[r][i] = v;
                    gm[r][i]  = fmaxf(gm[r][i], v);
                }
            if ((lane & 15) == 0) {
                const int q   = lane >> 4;
                const int cid = split * (CHUNKS * NSUB) + c * NSUB + jj;
                unsigned short* dst = cmax + (size_t)cid * N_TOK;
                #pragma unroll
                for (int r = 0; r < RT; ++r) {
                    ushort4 v;
                    v.x = ub16(mxc[r][0]);
                    v.y = ub16(mxc[r][1]);
                    v.z = ub16(mxc[r][2]);
                    v.w = ub16(mxc[r][3]);
                    // tokens (mtb+r)*16 + q*4 + {0..3}: one 8 B store
                    *(ushort4*)(dst + (mtb + r) * 16 + q * 4) = v;
                }
            }
        }
    }

    if ((lane & 15) == 0) {
        int q = lane >> 4;
        #pragma unroll
        for (int r = 0; r < RT; ++r)
            #pragma unroll
            for (int i = 0; i < 4; ++i) {
                int tok = (mtb + r) * 16 + q * 4 + i;
                atomicMax(&tokmax[tok], mono(gm[r][i]));
            }
    }
}

// ---------------------------------------------------------------------------
// Rescore: one wave per token, 4 tokens per block.
// Read 128 sub-chunk upper-bounds (cid-major gather), qualify vs
// tokmax - MARGIN, exact fp32 rescore of qualifying 64-code sub-chunks with
// COALESCED loads: one float4 load covers 4 complete code rows (lane l reads
// row i*4 + (l>>4), bytes (l&15)*16), 16-lane xor-tree completes each dot.
// ---------------------------------------------------------------------------
__global__ __launch_bounds__(256)
void rescore_kernel(const unsigned short* __restrict__ cmax,
                    const unsigned* __restrict__ tokmax,
                    const float* __restrict__ z,
                    const float* __restrict__ emb,
                    const float* __restrict__ invn,
                    int* __restrict__ idx, float* __restrict__ idxmap) {
    __shared__ float zsh[4][64];
    const int tid   = threadIdx.x;
    const int lane  = tid & 63;
    const int wv    = tid >> 6;
    const int token = blockIdx.x * 4 + wv;

    // cooperative z load: lane = channel, token's (b, h*64+w)
    {
        const int b = token >> 12, hw = token & 4095;
        zsh[wv][lane] = z[(size_t)b * (C_ * H_ * W_) + (size_t)lane * (H_ * W_) + hw];
    }
    __syncthreads();

    const float4 zr = ((const float4*)zsh[wv])[lane & 15];
    const float thrf = demono(tokmax[token]) - MARGIN;

    // cid-major bounds: cmax[cid][token]; lane -> cid, cid+64
    const unsigned short* cm = cmax + token;
    float ub0 = demono(((unsigned)cm[(size_t)lane * N_TOK]) << 16);
    float ub1 = demono(((unsigned)cm[(size_t)(64 + lane) * N_TOK]) << 16);
    unsigned long long q0 = __ballot(ub0 >= thrf);
    unsigned long long q1 = __ballot(ub1 >= thrf);

    float bv = -1e30f;
    int   bc = 0x7FFFFFFF;
    const int g  = lane >> 4;      // row-group 0..3
    const int li = lane & 15;

    #pragma unroll
    for (int half = 0; half < 2; ++half) {
        unsigned long long q = half ? q1 : q0;
        const int cb = half ? 64 : 0;
        while (q) {
            const int cid = cb + (__ffsll(q) - 1);
            q &= q - 1;
            const int rbase = cid * 64;       // first code of sub-chunk
            #pragma unroll
            for (int i = 0; i < 16; ++i) {
                const int code = rbase + i * 4 + g;
                const float4 e = ((const float4*)(emb + (size_t)code * DIMS))[li];
                float s = zr.x * e.x;
                s = fmaf(zr.y, e.y, s);
                s = fmaf(zr.z, e.z, s);
                s = fmaf(zr.w, e.w, s);
                s += __shfl_xor(s, 1, 64);
                s += __shfl_xor(s, 2, 64);
                s += __shfl_xor(s, 4, 64);
                s += __shfl_xor(s, 8, 64);
                const float val = s * invn[code];
                if (val > bv || (val == bv && code < bc)) { bv = val; bc = code; }
            }
        }
    }
    // merge the 4 row-groups (16-lane groups already agree)
    #pragma unroll
    for (int off = 1; off < 64; off <<= 1) {
        float ov = __shfl_xor(bv, off, 64);
        int   oc = __shfl_xor(bc, off, 64);
        if (ov > bv || (ov == bv && oc < bc)) { bv = ov; bc = oc; }
    }
    if (lane == 0) {
        idx[token]    = bc;
        idxmap[token] = (float)bc;
    }
}

// ---------------------------------------------------------------------------
// K3: gather z_q, out = zv + (q - zv), SSE partial, histogram.
// ---------------------------------------------------------------------------
__global__ void gather_loss_kernel(const float* __restrict__ z,
                                   const float* __restrict__ emb,
                                   const int* __restrict__ idx,
                                   float* __restrict__ out,
                                   float* __restrict__ partial,
                                   int* __restrict__ hist) {
    __shared__ float red[256];
    const int tid  = threadIdx.x;
    const int lane = tid & 63;   // w
    const int wave = tid >> 6;
    const int bt   = blockIdx.x; // 0..511
    const int b    = bt >> 6;
    const int h    = bt & 63;

    const int t  = bt * 64 + lane;
    const int id = idx[t];
    const long base = (long)b * (C_ * H_ * W_) + h * W_ + lane;

    float sse = 0.f;
    #pragma unroll
    for (int cc = 0; cc < 16; ++cc) {
        const int c = wave * 16 + cc;
        const float q  = emb[id * DIMS + c];
        const float zv = z[base + (long)c * (H_ * W_)];
        out[base + (long)c * (H_ * W_)] = zv + (q - zv);  // exact ref expression
        const float d = q - zv;
        sse += d * d;
    }

    red[tid] = sse;
    __syncthreads();
    for (int s = 128; s > 0; s >>= 1) {
        if (tid < s) red[tid] += red[tid + s];
        __syncthreads();
    }
    if (tid == 0) partial[bt] = red[0];
    if (wave == 0) atomicAdd(&hist[id], 1);
}

// ---------------------------------------------------------------------------
// K4: finalize loss + perplexity. One block of 256 threads.
// ---------------------------------------------------------------------------
__global__ void finalize_kernel(const float* __restrict__ partial,
                                const int* __restrict__ hist,
                                float* __restrict__ out_scal) {
    __shared__ double red[256];
    const int tid = threadIdx.x;

    double s = 0.0;
    for (int i = tid; i < 512; i += 256) s += (double)partial[i];
    red[tid] = s;
    __syncthreads();
    for (int st = 128; st > 0; st >>= 1) {
        if (tid < st) red[tid] += red[tid + st];
        __syncthreads();
    }
    const double sse = red[0];
    __syncthreads();

    double e = 0.0;
    for (int k = tid; k < NUM_EMBED; k += 256) {
        float p = (float)hist[k] / (float)N_TOK;
        e += (double)(p * logf(p + 1e-10f));
    }
    red[tid] = e;
    __syncthreads();
    for (int st = 128; st > 0; st >>= 1) {
        if (tid < st) red[tid] += red[tid + st];
        __syncthreads();
    }
    if (tid == 0) {
        out_scal[0] = (float)(1.25 * sse / (double)N_ELEM);
        out_scal[1] = expf(-(float)red[0]);
    }
}

// ---------------------------------------------------------------------------
extern "C" void kernel_launch(void* const* d_in, const int* in_sizes, int n_in,
                              void* d_out, int out_size, void* d_ws, size_t ws_size,
                              hipStream_t stream) {
    const float* z   = (const float*)d_in[0];
    const float* emb = (const float*)d_in[1];
    float* o = (float*)d_out;

    // workspace layout (5.57 MB base; proven available)
    char* ws = (char*)d_ws;
    v8s*  af      = (v8s*)ws;                                      // 4 MB
    v8s*  ef      = (v8s*)(ws + 4194304);                          // 1 MB
    unsigned* tokmax = (unsigned*)(ws + 5242880);                  // 128 KB
    int*   idx     = (int*)(ws + 5373952);                         // 128 KB
    float* invn    = (float*)(ws + 5505024);                       // 32 KB
    int*   hist    = (int*)(ws + 5537792);                         // 32 KB
    float* partial = (float*)(ws + 5570560);                       // 2 KB

    float* out_q      = o;                  // 2097152 floats
    float* out_scal   = o + N_ELEM;         // loss, perplexity
    float* out_idxmap = o + N_ELEM + 2;     // 32768 floats

    // cmax: u16[128][32768] = 8 MB, cid-major. Prefer workspace if large
    // enough; otherwise the out_q region (8.39 MB needed, 8.51 MB available;
    // written by pass1, read by rescore, overwritten by gather_loss after).
    unsigned short* cmaxb;
    if (ws_size >= (size_t)5572608 + 8388608)
        cmaxb = (unsigned short*)(ws + 5572608);
    else
        cmaxb = (unsigned short*)o;

    hipMemsetAsync(tokmax, 0, N_TOK * sizeof(unsigned), stream);
    hipMemsetAsync(hist,   0, NUM_EMBED * sizeof(int), stream);

    invnorm_kernel<<<NUM_EMBED / 4, 256, 0, stream>>>(emb, invn);
    en_frag_kernel<<<256, 256, 0, stream>>>(emb, invn, ef);
    z_prep_kernel<<<512, 256, 0, stream>>>(z, af);
    pass1_kernel<<<512, 512, 0, stream>>>(af, ef, tokmax, cmaxb);
    rescore_kernel<<<N_TOK / 4, 256, 0, stream>>>(cmaxb, tokmax, z, emb, invn,
                                                  idx, out_idxmap);
    gather_loss_kernel<<<N_TOK / 64, 256, 0, stream>>>(z, emb, idx, out_q, partial, hist);
    finalize_kernel<<<1, 256, 0, stream>>>(partial, hist, out_scal);
}